// Round 1
// baseline (131.487 us; speedup 1.0000x reference)
//
#include <hip/hip_runtime.h>
#include <hip/hip_bf16.h>
#include <math.h>
#include <string.h>

constexpr int VOCAB  = 32000;
constexpr int D      = 128;
constexpr int T      = 32;
constexpr int NCELLS = 8 * 100 * 64;   // 51200
constexpr int NCHUNK = 4;              // D split into 4 chunks of 32 dims
constexpr int CDIM   = D / NCHUNK;     // 32 dims = 64 B bf16 per token slice

// ---- helpers
__device__ inline ushort f2bf(float f) {
    uint32_t u;
    memcpy(&u, &f, 4);
    u += 0x7FFFu + ((u >> 16) & 1u);   // RTN-even
    return (ushort)(u >> 16);
}

__device__ inline float bf_lo(uint32_t u) {
    uint32_t b = u << 16; float f; memcpy(&f, &b, 4); return f;
}
__device__ inline float bf_hi(uint32_t u) {
    uint32_t b = u & 0xFFFF0000u; float f; memcpy(&f, &b, 4); return f;
}

// Fast exact-erf GELU: Abramowitz-Stegun 7.1.26 (|erf err| <= 1.5e-7).
__device__ inline float gelu_fast(float xv) {
    const float is2 = 0.70710678118654752440f;
    float y  = xv * is2;
    float av = fabsf(y);
    float t  = __builtin_amdgcn_rcpf(__builtin_fmaf(0.3275911f, av, 1.0f));
    float p  = 0.254829592f + t * (-0.284496736f + t * (1.421413741f
             + t * (-1.453152027f + t * 1.061405429f)));
    float e  = __expf(-av * av);
    float er = 1.0f - p * t * e;
    er = copysignf(er, y);
    return 0.5f * xv * (1.0f + er);
}

// Kernel 1: convert W_embed f32 -> bf16 chunked [4][VOCAB][32]; also zero-init
// out (grid covers 1.024M threads >= NCELLS).
__global__ __launch_bounds__(256) void convert_W_kernel(
    const float* __restrict__ W, ushort* __restrict__ Wb, float* __restrict__ out)
{
    const int i = blockIdx.x * blockDim.x + threadIdx.x;  // float4 group id
    const int v = i >> 5;        // vocab row (32 groups of 4 dims per row)
    const int k = i & 31;
    const int chunk = k >> 3;    // 8 groups (32 dims) per chunk
    const int sub   = k & 7;

    float4 src = reinterpret_cast<const float4*>(W)[i];
    ushort4 o;
    o.x = f2bf(src.x); o.y = f2bf(src.y); o.z = f2bf(src.z); o.w = f2bf(src.w);
    reinterpret_cast<ushort4*>(Wb)[((size_t)chunk * VOCAB + v) * 8 + sub] = o;

    if (i < NCELLS) out[i] = 0.0f;
}

// Kernel 2: one wave per (cell, chunk). blockIdx%8 steers chunks to XCD pairs:
// each XCD's L2 caches one 2.05 MB table slice (49% of 4 MiB L2) instead of the
// previous 4.1 MB (98% -> thrash to L3).
// Lane layout: j = lane&7 (8B = 4 dims of the 64B token slice), q = lane>>3
// (token subgroup). Per iter the wave loads 8 token rows (tokens 8i+q),
// 8 B/lane (uint2 = 4 bf16 dims).
__global__ __launch_bounds__(256) void gather_kernel(
    const int*    __restrict__ x,       // [NCELLS, T]
    const ushort* __restrict__ Wb,      // [NCHUNK][VOCAB][CDIM] bf16 bits
    const float*  __restrict__ w_pred,  // [1, D]
    const float*  __restrict__ b_pred,  // [1]
    float*        __restrict__ out)     // [NCELLS] (zeroed by convert kernel)
{
    const int wave = threadIdx.x >> 6;
    const int lane = threadIdx.x & 63;

    const int slot  = blockIdx.x & 7;
    const int chunk = slot >> 1;               // 2 XCDs per chunk
    const int sub   = slot & 1;
    const int g     = blockIdx.x >> 3;         // 0..6399
    const int cell  = ((g << 1) + sub) * 4 + wave;

    const int j  = lane & 7;    // 8B group: dims 4j..4j+3 of the chunk slice
    const int q  = lane >> 3;   // token subgroup 0..7
    const int q4 = q << 2;

    // lane t (t = lane&31) holds token t's row offset (uint2 element units)
    int myidx  = __builtin_nontemporal_load(x + (size_t)cell * T + (lane & 31));
    int rowoff = myidx << 3;    // token * 8 uint2 per 64B row slice

    const uint2* __restrict__ tbl =
        reinterpret_cast<const uint2*>(Wb) + (size_t)chunk * (VOCAB * 8);

    float a0 = 0.0f, a1 = 0.0f, a2 = 0.0f, a3 = 0.0f;
    #pragma unroll
    for (int i = 0; i < T / 8; ++i) {
        int e = __builtin_amdgcn_ds_bpermute(q4 + (i << 5), rowoff); // token 8i+q
        uint2 v = tbl[(uint32_t)(e + j)];   // saddr + 32b voffset, 8B
        a0 += bf_lo(v.x); a1 += bf_hi(v.x);
        a2 += bf_lo(v.y); a3 += bf_hi(v.y);
    }

    // Reducing transpose across q-groups: butterfly that both sums the 8 token
    // subgroups and redistributes the 4 accumulators so each lane ends owning
    // exactly one dim (1 GELU/lane instead of 4).
    const int qb0 = q & 1;
    float k0 = qb0 ? a2 : a0;   // keep pair
    float k1 = qb0 ? a3 : a1;
    float g0 = qb0 ? a0 : a2;   // give pair
    float g1 = qb0 ? a1 : a3;
    k0 += __shfl_xor(g0, 8, 64);
    k1 += __shfl_xor(g1, 8, 64);

    const int qb1 = (q >> 1) & 1;
    float m  = qb1 ? k1 : k0;
    float gm = qb1 ? k0 : k1;
    m += __shfl_xor(gm, 16, 64);
    m += __shfl_xor(m, 32, 64);   // same dim, other token half

    // lane owns chunk-dim d; lanes 0..31 cover all 32 dims bijectively
    const int d = 4 * j + 2 * qb0 + qb1;
    float p  = m * (1.0f / (float)T);
    float gl = gelu_fast(p);
    float wv = w_pred[chunk * CDIM + d];
    float s  = gl * wv;

    #pragma unroll
    for (int off = 16; off >= 1; off >>= 1)
        s += __shfl_xor(s, off, 64);

    if (lane == 0) {
        if (chunk == 0) s += b_pred[0];
        atomicAdd(&out[cell], s);
    }
}

extern "C" void kernel_launch(void* const* d_in, const int* in_sizes, int n_in,
                              void* d_out, int out_size, void* d_ws, size_t ws_size,
                              hipStream_t stream) {
    const int*   x      = (const int*)  d_in[0];
    const float* W      = (const float*)d_in[1];
    const float* w_pred = (const float*)d_in[2];
    const float* b_pred = (const float*)d_in[3];
    float*       out    = (float*)d_out;
    ushort*      Wb     = (ushort*)d_ws;   // VOCAB*D*2 = 8.192 MB

    const int conv_groups = VOCAB * D / 4;                 // 1,024,000
    convert_W_kernel<<<conv_groups / 256, 256, 0, stream>>>(W, Wb, out);

    // 4 chunks x 12800 cell-blocks (4 cells per block) = 51200 blocks
    gather_kernel<<<NCHUNK * (NCELLS / 4), 256, 0, stream>>>(x, Wb, w_pred, b_pred, out);
}

// Round 2
// 105.139 us; speedup vs baseline: 1.2506x; 1.2506x over previous
//
#include <hip/hip_runtime.h>
#include <hip/hip_bf16.h>
#include <math.h>
#include <string.h>

constexpr int VOCAB  = 32000;
constexpr int D      = 128;
constexpr int T      = 32;
constexpr int NCELLS = 8 * 100 * 64;   // 51200

// ---- helpers
__device__ inline ushort f2bf(float f) {
    uint32_t u;
    memcpy(&u, &f, 4);
    u += 0x7FFFu + ((u >> 16) & 1u);   // RTN-even
    return (ushort)(u >> 16);
}

__device__ inline float bf_lo(uint32_t u) {
    uint32_t b = u << 16; float f; memcpy(&f, &b, 4); return f;
}
__device__ inline float bf_hi(uint32_t u) {
    uint32_t b = u & 0xFFFF0000u; float f; memcpy(&f, &b, 4); return f;
}

// Fast exact-erf GELU: Abramowitz-Stegun 7.1.26 (|erf err| <= 1.5e-7).
__device__ inline float gelu_fast(float xv) {
    const float is2 = 0.70710678118654752440f;
    float y  = xv * is2;
    float av = fabsf(y);
    float t  = __builtin_amdgcn_rcpf(__builtin_fmaf(0.3275911f, av, 1.0f));
    float p  = 0.254829592f + t * (-0.284496736f + t * (1.421413741f
             + t * (-1.453152027f + t * 1.061405429f)));
    float e  = __expf(-av * av);
    float er = 1.0f - p * t * e;
    er = copysignf(er, y);
    return 0.5f * xv * (1.0f + er);
}

// Kernel 1: convert W_embed f32 -> bf16, plain [VOCAB][D] layout (row = 256 B).
__global__ __launch_bounds__(256) void convert_W_kernel(
    const float* __restrict__ W, ushort* __restrict__ Wb)
{
    const int i = blockIdx.x * blockDim.x + threadIdx.x;  // float4 group id
    float4 src = reinterpret_cast<const float4*>(W)[i];
    ushort4 o;
    o.x = f2bf(src.x); o.y = f2bf(src.y); o.z = f2bf(src.z); o.w = f2bf(src.w);
    reinterpret_cast<ushort4*>(Wb)[i] = o;
}

// Kernel 2: ONE WAVE PER CELL. cell is wave-uniform (readfirstlane) so the 32
// token indices come in via s_load (scalar cache), each token row address is
// an SGPR base, and the 64-lane row read is saddr + lane*4 (row = 256 B
// exactly). No bpermute, no transpose, no atomics: wave owns the cell fully.
__global__ __launch_bounds__(256) void gather_kernel(
    const int*    __restrict__ x,       // [NCELLS, T]
    const ushort* __restrict__ Wb,      // [VOCAB][D] bf16 bits
    const float*  __restrict__ w_pred,  // [1, D]
    const float*  __restrict__ b_pred,  // [1]
    float*        __restrict__ out)     // [NCELLS]
{
    const int lane = threadIdx.x & 63;
    // force wave-uniformity so x loads become s_load and row bases stay SGPR
    const int cell = __builtin_amdgcn_readfirstlane(
        blockIdx.x * 4 + (threadIdx.x >> 6));

    const int* __restrict__ xc = x + (size_t)cell * T;

    // 4-way split accumulators to shorten the f32 add dependency chains
    float ax0 = 0.0f, ay0 = 0.0f, ax1 = 0.0f, ay1 = 0.0f;
    #pragma unroll
    for (int t = 0; t < T; t += 2) {
        int i0 = xc[t];
        int i1 = xc[t + 1];
        const uint32_t* r0 = reinterpret_cast<const uint32_t*>(Wb + (size_t)i0 * D);
        const uint32_t* r1 = reinterpret_cast<const uint32_t*>(Wb + (size_t)i1 * D);
        uint32_t v0 = r0[lane];   // saddr + (lane*4) voffset, 4 B
        uint32_t v1 = r1[lane];
        ax0 += bf_lo(v0); ay0 += bf_hi(v0);
        ax1 += bf_lo(v1); ay1 += bf_hi(v1);
    }
    float ax = ax0 + ax1;   // dim 2*lane
    float ay = ay0 + ay1;   // dim 2*lane + 1

    const float inv_t = 1.0f / (float)T;
    float g0 = gelu_fast(ax * inv_t);
    float g1 = gelu_fast(ay * inv_t);

    float2 wv = reinterpret_cast<const float2*>(w_pred)[lane];
    float s = __builtin_fmaf(g0, wv.x, g1 * wv.y);

    #pragma unroll
    for (int off = 32; off >= 1; off >>= 1)
        s += __shfl_xor(s, off, 64);

    if (lane == 0)
        out[cell] = s + b_pred[0];
}

extern "C" void kernel_launch(void* const* d_in, const int* in_sizes, int n_in,
                              void* d_out, int out_size, void* d_ws, size_t ws_size,
                              hipStream_t stream) {
    const int*   x      = (const int*)  d_in[0];
    const float* W      = (const float*)d_in[1];
    const float* w_pred = (const float*)d_in[2];
    const float* b_pred = (const float*)d_in[3];
    float*       out    = (float*)d_out;
    ushort*      Wb     = (ushort*)d_ws;   // VOCAB*D*2 = 8.192 MB

    const int conv_groups = VOCAB * D / 4;                 // 1,024,000
    convert_W_kernel<<<conv_groups / 256, 256, 0, stream>>>(W, Wb);

    // one wave per cell: 51200 waves = 12800 blocks of 4 waves
    gather_kernel<<<NCELLS / 4, 256, 0, stream>>>(x, Wb, w_pred, b_pred, out);
}